// Round 1
// 1182.080 us; speedup vs baseline: 1.9527x; 1.9527x over previous
//
#include <hip/hip_runtime.h>
#include <math.h>

#define NROWS 32768   // B*T
#define DDIM  512
#define KDIM  2048

typedef unsigned short u16;
typedef unsigned int   u32;
using f32x4  = __attribute__((ext_vector_type(4))) float;
using bf16x8 = __attribute__((ext_vector_type(8))) __bf16;

// ------------------------------- helpers -----------------------------------
__device__ __forceinline__ u32 rne2(float x, float y) {
    // pack two fp32 -> two RNE bf16 in one dword (low = x)
    u32 vx = __float_as_uint(x), vy = __float_as_uint(y);
    vx = vx + 0x7fffu + ((vx >> 16) & 1u);
    vy = vy + 0x7fffu + ((vy >> 16) & 1u);
    return (vx >> 16) | (vy & 0xffff0000u);
}

// split fp32 into hi (truncated top 16 bits) + lo (RNE bf16 of residual)
// x ~= hi + lo with |err| <~ 2^-17 |x|
__device__ __forceinline__ void split2(float x, float y, u32 &hp, u32 &lp) {
    u32 ux = __float_as_uint(x), uy = __float_as_uint(y);
    u32 hxm = ux & 0xffff0000u, hym = uy & 0xffff0000u;
    hp = (ux >> 16) | hym;
    float rx = x - __uint_as_float(hxm);
    float ry = y - __uint_as_float(hym);
    lp = rne2(rx, ry);
}

__device__ __forceinline__ float gumbel(float u) {
    return -logf(-logf(u + 1e-10f) + 1e-10f);
}

// --------------------- row inverse-norms (h) --------------------------------
__global__ __launch_bounds__(256) void rownorms(
    const float* __restrict__ X, float* __restrict__ OUT)
{
    int wv = threadIdx.x >> 6, lane = threadIdx.x & 63;
    int row = blockIdx.x * 4 + wv;
    const float4* src = (const float4*)(X + (size_t)row * DDIM);
    float4 a = src[lane], b = src[lane + 64];
    float ss = a.x*a.x + a.y*a.y + a.z*a.z + a.w*a.w
             + b.x*b.x + b.y*b.y + b.z*b.z + b.w*b.w;
    #pragma unroll
    for (int off = 32; off > 0; off >>= 1) ss += __shfl_down(ss, off, 64);
    if (lane == 0) OUT[row] = 1.0f / fmaxf(sqrtf(ss), 1e-6f);
}

// ------------- codebook prep: inv-norms + raw hi/lo bf16 split --------------
__global__ __launch_bounds__(256) void prep_cb(
    const float* __restrict__ CB, u16* __restrict__ HI, u16* __restrict__ LO,
    float* __restrict__ INVC)
{
    int wv = threadIdx.x >> 6, lane = threadIdx.x & 63;
    int row = blockIdx.x * 4 + wv;
    const float4* src = (const float4*)(CB + (size_t)row * DDIM);
    float4 a = src[lane], b = src[lane + 64];
    float ss = a.x*a.x + a.y*a.y + a.z*a.z + a.w*a.w
             + b.x*b.x + b.y*b.y + b.z*b.z + b.w*b.w;
    #pragma unroll
    for (int off = 32; off > 0; off >>= 1) ss += __shfl_down(ss, off, 64);
    if (lane == 0) INVC[row] = 1.0f / fmaxf(sqrtf(ss), 1e-6f);

    u32 h0, h1, l0, l1;
    split2(a.x, a.y, h0, l0); split2(a.z, a.w, h1, l1);
    *(uint2*)(HI + (size_t)row * DDIM + lane * 4) = make_uint2(h0, h1);
    *(uint2*)(LO + (size_t)row * DDIM + lane * 4) = make_uint2(l0, l1);
    split2(b.x, b.y, h0, l0); split2(b.z, b.w, h1, l1);
    *(uint2*)(HI + (size_t)row * DDIM + 256 + lane * 4) = make_uint2(h0, h1);
    *(uint2*)(LO + (size_t)row * DDIM + 256 + lane * 4) = make_uint2(l0, l1);
}

// ---- codebook transpose: CBT[d][k] = bf16(cb[k][d] * invc[k])  [512 x 2048]
__global__ __launch_bounds__(256) void transpose_cb(
    const float* __restrict__ CB, const float* __restrict__ INVC,
    u16* __restrict__ CBT)
{
    __shared__ __align__(16) u16 T[64][72];
    int t = threadIdx.x;
    int k0 = blockIdx.x * 64, d0 = blockIdx.y * 64;
    int r = t >> 2, q = (t & 3) * 16;
    float ic = INVC[k0 + r];
    const float* src = CB + (size_t)(k0 + r) * DDIM + d0 + q;
    float4 f0 = *(const float4*)(src);
    float4 f1 = *(const float4*)(src + 4);
    float4 f2 = *(const float4*)(src + 8);
    float4 f3 = *(const float4*)(src + 12);
    f0.x *= ic; f0.y *= ic; f0.z *= ic; f0.w *= ic;
    f1.x *= ic; f1.y *= ic; f1.z *= ic; f1.w *= ic;
    f2.x *= ic; f2.y *= ic; f2.z *= ic; f2.w *= ic;
    f3.x *= ic; f3.y *= ic; f3.z *= ic; f3.w *= ic;
    uint4 p0 = make_uint4(rne2(f0.x,f0.y), rne2(f0.z,f0.w), rne2(f1.x,f1.y), rne2(f1.z,f1.w));
    uint4 p1 = make_uint4(rne2(f2.x,f2.y), rne2(f2.z,f2.w), rne2(f3.x,f3.y), rne2(f3.z,f3.w));
    *(uint4*)&T[r][q]     = p0;
    *(uint4*)&T[r][q + 8] = p1;
    __syncthreads();
    int d = t >> 2, kq = (t & 3) * 16;
    u16 v[16];
    #pragma unroll
    for (int i = 0; i < 16; ++i) v[i] = T[kq + i][d];
    uint4 o0 = make_uint4((u32)v[0]  | ((u32)v[1]  << 16), (u32)v[2]  | ((u32)v[3]  << 16),
                          (u32)v[4]  | ((u32)v[5]  << 16), (u32)v[6]  | ((u32)v[7]  << 16));
    uint4 o1 = make_uint4((u32)v[8]  | ((u32)v[9]  << 16), (u32)v[10] | ((u32)v[11] << 16),
                          (u32)v[12] | ((u32)v[13] << 16), (u32)v[14] | ((u32)v[15] << 16));
    u16* dst = CBT + (size_t)(d0 + d) * KDIM + k0 + kq;
    *(uint4*)dst       = o0;
    *(uint4*)(dst + 8) = o1;
}

// --------- GEMM1: logits = 2*(h.cb^T)*invh*invc - 2 + g(u)  (split bf16) ----
#define LDS1 40
__global__ __launch_bounds__(256) void gemm1_split(
    const float* __restrict__ H, const u16* __restrict__ BH,
    const u16* __restrict__ BL, const float* __restrict__ INVH,
    const float* __restrict__ INVC, const float* __restrict__ U,
    float* __restrict__ L)
{
    __shared__ __align__(16) u16 Ah[128 * LDS1];
    __shared__ __align__(16) u16 Al[128 * LDS1];
    __shared__ __align__(16) u16 Bh[128 * LDS1];
    __shared__ __align__(16) u16 Bl[128 * LDS1];

    int t = threadIdx.x;
    int bid = blockIdx.x;
    int w = ((bid & 7) << 9) | (bid >> 3);   // XCD-chunked bijective swizzle (4096 = 8*512)
    int m0 = (w >> 4) * 128;                 // N (rows) block
    int n0 = (w & 15) * 128;                 // K (codes) block

    int srow = t >> 1;
    int scol = (t & 1) << 4;

    const float* ga  = H  + (size_t)(m0 + srow) * DDIM + scol;
    const u16*   gbh = BH + (size_t)(n0 + srow) * DDIM + scol;
    const u16*   gbl = BL + (size_t)(n0 + srow) * DDIM + scol;

    float4 a0 = *(const float4*)(ga);
    float4 a1 = *(const float4*)(ga + 4);
    float4 a2 = *(const float4*)(ga + 8);
    float4 a3 = *(const float4*)(ga + 12);
    uint4  b0 = *(const uint4*)(gbh);
    uint4  b1 = *(const uint4*)(gbh + 8);
    uint4  c0 = *(const uint4*)(gbl);
    uint4  c1 = *(const uint4*)(gbl + 8);

    f32x4 acc[4][4];
    #pragma unroll
    for (int i = 0; i < 4; ++i)
        #pragma unroll
        for (int j = 0; j < 4; ++j)
            acc[i][j] = (f32x4){0.0f, 0.0f, 0.0f, 0.0f};

    int lane = t & 63;
    int wid  = t >> 6;
    int wr = (wid >> 1) << 6;
    int wc = (wid & 1) << 6;
    int frow = lane & 15;
    int fk   = (lane >> 4) << 3;
    int asb  = srow * LDS1 + scol;

    #pragma unroll 1
    for (int kt = 0; kt < 16; ++kt) {
        uint4 hA, lA;
        split2(a0.x, a0.y, hA.x, lA.x);
        split2(a0.z, a0.w, hA.y, lA.y);
        split2(a1.x, a1.y, hA.z, lA.z);
        split2(a1.z, a1.w, hA.w, lA.w);
        *(uint4*)&Ah[asb] = hA;
        *(uint4*)&Al[asb] = lA;
        split2(a2.x, a2.y, hA.x, lA.x);
        split2(a2.z, a2.w, hA.y, lA.y);
        split2(a3.x, a3.y, hA.z, lA.z);
        split2(a3.z, a3.w, hA.w, lA.w);
        *(uint4*)&Ah[asb + 8] = hA;
        *(uint4*)&Al[asb + 8] = lA;
        *(uint4*)&Bh[asb]     = b0;
        *(uint4*)&Bh[asb + 8] = b1;
        *(uint4*)&Bl[asb]     = c0;
        *(uint4*)&Bl[asb + 8] = c1;
        __syncthreads();
        if (kt < 15) {            // issue next tile's loads; complete under MFMAs
            ga += 32; gbh += 32; gbl += 32;
            a0 = *(const float4*)(ga);
            a1 = *(const float4*)(ga + 4);
            a2 = *(const float4*)(ga + 8);
            a3 = *(const float4*)(ga + 12);
            b0 = *(const uint4*)(gbh);
            b1 = *(const uint4*)(gbh + 8);
            c0 = *(const uint4*)(gbl);
            c1 = *(const uint4*)(gbl + 8);
        }
        bf16x8 vbh[4], vbl[4];
        #pragma unroll
        for (int j = 0; j < 4; ++j) {
            int off = (wc + j * 16 + frow) * LDS1 + fk;
            vbh[j] = *(const bf16x8*)&Bh[off];
            vbl[j] = *(const bf16x8*)&Bl[off];
        }
        #pragma unroll
        for (int i = 0; i < 4; ++i) {
            int off = (wr + i * 16 + frow) * LDS1 + fk;
            bf16x8 vah = *(const bf16x8*)&Ah[off];
            bf16x8 val = *(const bf16x8*)&Al[off];
            #pragma unroll
            for (int j = 0; j < 4; ++j) {
                acc[i][j] = __builtin_amdgcn_mfma_f32_16x16x32_bf16(vah, vbh[j], acc[i][j], 0, 0, 0);
                acc[i][j] = __builtin_amdgcn_mfma_f32_16x16x32_bf16(vah, vbl[j], acc[i][j], 0, 0, 0);
                acc[i][j] = __builtin_amdgcn_mfma_f32_16x16x32_bf16(val, vbh[j], acc[i][j], 0, 0, 0);
            }
        }
        __syncthreads();
    }

    float invc[4];
    #pragma unroll
    for (int j = 0; j < 4; ++j) invc[j] = INVC[n0 + wc + j * 16 + frow];
    int r0 = (lane >> 4) << 2;
    #pragma unroll
    for (int i = 0; i < 4; ++i) {
        #pragma unroll
        for (int r = 0; r < 4; ++r) {
            int grow = m0 + wr + i * 16 + r0 + r;
            float ih = INVH[grow];
            const float* urow = U + (size_t)grow * KDIM + n0 + wc + frow;
            float*       lrow = L + (size_t)grow * KDIM + n0 + wc + frow;
            #pragma unroll
            for (int j = 0; j < 4; ++j) {
                float s = acc[i][j][r] * ih * invc[j];
                lrow[j * 16] = 2.0f * s - 2.0f + gumbel(urow[j * 16]);
            }
        }
    }
}

// ---------------- softmax + argmax per row (in-place logits -> q) -----------
__global__ __launch_bounds__(256) void softmax_rows(
    float* __restrict__ L, float* __restrict__ out_idx_f, int* __restrict__ ws_idx)
{
    int row = blockIdx.x, t = threadIdx.x;
    int lane = t & 63, wv = t >> 6;
    float* lr = L + (size_t)row * KDIM;
    float4 v0 = ((float4*)lr)[t];
    float4 v1 = ((float4*)lr)[t + 256];
    int c0 = t * 4, c1 = 1024 + t * 4;
    float m = v0.x; int mi = c0;
    if (v0.y > m) { m = v0.y; mi = c0 + 1; }
    if (v0.z > m) { m = v0.z; mi = c0 + 2; }
    if (v0.w > m) { m = v0.w; mi = c0 + 3; }
    if (v1.x > m) { m = v1.x; mi = c1; }
    if (v1.y > m) { m = v1.y; mi = c1 + 1; }
    if (v1.z > m) { m = v1.z; mi = c1 + 2; }
    if (v1.w > m) { m = v1.w; mi = c1 + 3; }
    #pragma unroll
    for (int off = 32; off > 0; off >>= 1) {
        float om = __shfl_down(m, off, 64);
        int   oi = __shfl_down(mi, off, 64);
        if (om > m || (om == m && oi < mi)) { m = om; mi = oi; }
    }
    __shared__ float wm[4]; __shared__ int wi[4]; __shared__ float wsum[4];
    if (lane == 0) { wm[wv] = m; wi[wv] = mi; }
    __syncthreads();
    float M = wm[0]; int MI = wi[0];
    #pragma unroll
    for (int k = 1; k < 4; ++k)
        if (wm[k] > M || (wm[k] == M && wi[k] < MI)) { M = wm[k]; MI = wi[k]; }
    v0.x = expf(v0.x - M); v0.y = expf(v0.y - M);
    v0.z = expf(v0.z - M); v0.w = expf(v0.w - M);
    v1.x = expf(v1.x - M); v1.y = expf(v1.y - M);
    v1.z = expf(v1.z - M); v1.w = expf(v1.w - M);
    float s = v0.x + v0.y + v0.z + v0.w + v1.x + v1.y + v1.z + v1.w;
    #pragma unroll
    for (int off = 32; off > 0; off >>= 1) s += __shfl_down(s, off, 64);
    if (lane == 0) wsum[wv] = s;
    __syncthreads();
    float inv = 1.0f / (wsum[0] + wsum[1] + wsum[2] + wsum[3]);
    v0.x *= inv; v0.y *= inv; v0.z *= inv; v0.w *= inv;
    v1.x *= inv; v1.y *= inv; v1.z *= inv; v1.w *= inv;
    ((float4*)lr)[t] = v0;
    ((float4*)lr)[t + 256] = v1;
    if (t == 0) { out_idx_f[row] = (float)MI; ws_idx[row] = MI; }
}

// --------- GEMM2: c_tilde = q . cb_n   (plain bf16 MFMA, B = CBT^T form) ----
#define LDS2 72
__global__ __launch_bounds__(256) void gemm2_bf16(
    const float* __restrict__ Q, const u16* __restrict__ CBT, float* __restrict__ CT)
{
    __shared__ __align__(16) u16 As[128 * LDS2];
    __shared__ __align__(16) u16 Bs[128 * LDS2];
    int t = threadIdx.x;
    int bid = blockIdx.x;
    int w = ((bid & 7) << 7) | (bid >> 3);   // 1024 = 8*128, bijective
    int m0 = (w >> 2) * 128;                 // N rows
    int n0 = (w & 3) * 128;                  // D cols
    int srow = t >> 1;
    int scol = (t & 1) << 5;
    const float* gq = Q   + (size_t)(m0 + srow) * KDIM + scol;
    const u16*   gb = CBT + (size_t)(n0 + srow) * KDIM + scol;

    float4 q0 = *(const float4*)(gq);
    float4 q1 = *(const float4*)(gq + 4);
    float4 q2 = *(const float4*)(gq + 8);
    float4 q3 = *(const float4*)(gq + 12);
    float4 q4 = *(const float4*)(gq + 16);
    float4 q5 = *(const float4*)(gq + 20);
    float4 q6 = *(const float4*)(gq + 24);
    float4 q7 = *(const float4*)(gq + 28);
    uint4 b0 = *(const uint4*)(gb);
    uint4 b1 = *(const uint4*)(gb + 8);
    uint4 b2 = *(const uint4*)(gb + 16);
    uint4 b3 = *(const uint4*)(gb + 24);

    f32x4 acc[4][4];
    #pragma unroll
    for (int i = 0; i < 4; ++i)
        #pragma unroll
        for (int j = 0; j < 4; ++j)
            acc[i][j] = (f32x4){0.0f, 0.0f, 0.0f, 0.0f};

    int lane = t & 63, wid = t >> 6;
    int wr = (wid >> 1) << 6;
    int wc = (wid & 1) << 6;
    int frow = lane & 15;
    int fk   = (lane >> 4) << 3;
    int asb  = srow * LDS2 + scol;

    #pragma unroll 1
    for (int kt = 0; kt < 32; ++kt) {
        uint4 pa;
        pa = make_uint4(rne2(q0.x,q0.y), rne2(q0.z,q0.w), rne2(q1.x,q1.y), rne2(q1.z,q1.w));
        *(uint4*)&As[asb] = pa;
        pa = make_uint4(rne2(q2.x,q2.y), rne2(q2.z,q2.w), rne2(q3.x,q3.y), rne2(q3.z,q3.w));
        *(uint4*)&As[asb + 8] = pa;
        pa = make_uint4(rne2(q4.x,q4.y), rne2(q4.z,q4.w), rne2(q5.x,q5.y), rne2(q5.z,q5.w));
        *(uint4*)&As[asb + 16] = pa;
        pa = make_uint4(rne2(q6.x,q6.y), rne2(q6.z,q6.w), rne2(q7.x,q7.y), rne2(q7.z,q7.w));
        *(uint4*)&As[asb + 24] = pa;
        *(uint4*)&Bs[asb]      = b0;
        *(uint4*)&Bs[asb + 8]  = b1;
        *(uint4*)&Bs[asb + 16] = b2;
        *(uint4*)&Bs[asb + 24] = b3;
        __syncthreads();
        if (kt < 31) {
            gq += 64; gb += 64;
            q0 = *(const float4*)(gq);
            q1 = *(const float4*)(gq + 4);
            q2 = *(const float4*)(gq + 8);
            q3 = *(const float4*)(gq + 12);
            q4 = *(const float4*)(gq + 16);
            q5 = *(const float4*)(gq + 20);
            q6 = *(const float4*)(gq + 24);
            q7 = *(const float4*)(gq + 28);
            b0 = *(const uint4*)(gb);
            b1 = *(const uint4*)(gb + 8);
            b2 = *(const uint4*)(gb + 16);
            b3 = *(const uint4*)(gb + 24);
        }
        #pragma unroll
        for (int kk = 0; kk < 2; ++kk) {
            bf16x8 vb[4];
            #pragma unroll
            for (int j = 0; j < 4; ++j)
                vb[j] = *(const bf16x8*)&Bs[(wc + j * 16 + frow) * LDS2 + kk * 32 + fk];
            #pragma unroll
            for (int i = 0; i < 4; ++i) {
                bf16x8 va = *(const bf16x8*)&As[(wr + i * 16 + frow) * LDS2 + kk * 32 + fk];
                #pragma unroll
                for (int j = 0; j < 4; ++j)
                    acc[i][j] = __builtin_amdgcn_mfma_f32_16x16x32_bf16(va, vb[j], acc[i][j], 0, 0, 0);
            }
        }
        __syncthreads();
    }

    int r0 = (lane >> 4) << 2;
    #pragma unroll
    for (int i = 0; i < 4; ++i) {
        #pragma unroll
        for (int r = 0; r < 4; ++r) {
            int grow = m0 + wr + i * 16 + r0 + r;
            float* crow = CT + (size_t)grow * DDIM + n0 + wc + frow;
            #pragma unroll
            for (int j = 0; j < 4; ++j) crow[j * 16] = acc[i][j][r];
        }
    }
}

// ---------------- gather c_hard/c_quant + per-row squared-diff partials -----
__global__ __launch_bounds__(256) void gather_loss(
    const u16* __restrict__ CBH, const u16* __restrict__ CBL,
    const float* __restrict__ INVC, const int* __restrict__ ws_idx,
    const float* __restrict__ Ct, const float* __restrict__ H,
    const float* __restrict__ INVH,
    float* __restrict__ c_hard, float* __restrict__ c_quant,
    float* __restrict__ partials)
{
    int row = blockIdx.x, t = threadIdx.x;
    int idx = ws_idx[row];
    float ic = INVC[idx], ih = INVH[row];
    u32 hp = ((const u32*)(CBH + (size_t)idx * DDIM))[t];
    u32 lp = ((const u32*)(CBL + (size_t)idx * DDIM))[t];
    float cx = (__uint_as_float(hp << 16) + __uint_as_float(lp << 16)) * ic;
    float cy = (__uint_as_float(hp & 0xffff0000u) + __uint_as_float(lp & 0xffff0000u)) * ic;
    float2 cv; cv.x = cx; cv.y = cy;
    ((float2*)(c_hard  + (size_t)row * DDIM))[t] = cv;
    ((float2*)(c_quant + (size_t)row * DDIM))[t] = cv;
    float2 hv = ((const float2*)(H  + (size_t)row * DDIM))[t];
    float2 ct = ((const float2*)(Ct + (size_t)row * DDIM))[t];
    float dx = ct.x - hv.x * ih, dy = ct.y - hv.y * ih;
    __shared__ float red[256];
    red[t] = dx * dx + dy * dy;
    __syncthreads();
    for (int s = 128; s > 0; s >>= 1) {
        if (t < s) red[t] += red[t + s];
        __syncthreads();
    }
    if (t == 0) partials[row] = red[0];
}

__global__ __launch_bounds__(1024) void loss_reduce(
    const float* __restrict__ partials, float* __restrict__ loss_out)
{
    int t = threadIdx.x;
    float s = 0.0f;
    for (int i = t; i < NROWS; i += 1024) s += partials[i];
    __shared__ float red[1024];
    red[t] = s;
    __syncthreads();
    for (int st = 512; st > 0; st >>= 1) {
        if (t < st) red[t] += red[t + st];
        __syncthreads();
    }
    if (t == 0) loss_out[0] = red[0] * (1.25f / ((float)NROWS * (float)DDIM));
}

extern "C" void kernel_launch(void* const* d_in, const int* in_sizes, int n_in,
                              void* d_out, int out_size, void* d_ws, size_t ws_size,
                              hipStream_t stream) {
    const float* h  = (const float*)d_in[0];
    const float* cb = (const float*)d_in[1];
    const float* u  = (const float*)d_in[2];

    float* out     = (float*)d_out;
    float* q       = out;                                   // N*K
    float* c_tilde = out + (size_t)NROWS * KDIM;            // N*D
    float* c_hard  = c_tilde + (size_t)NROWS * DDIM;
    float* c_quant = c_hard  + (size_t)NROWS * DDIM;
    float* loss    = c_quant + (size_t)NROWS * DDIM;        // 1
    float* idx_f   = loss + 1;                              // N

    // workspace (~6.4 MB total, well under previous 68 MB usage)
    u16* cb_hi = (u16*)d_ws;                                // K*D bf16 (raw hi)
    u16* cb_lo = cb_hi + (size_t)KDIM * DDIM;               // K*D bf16 (residual)
    u16* cbT   = cb_lo + (size_t)KDIM * DDIM;               // D*K bf16 (normalized, transposed)
    float* invn_h  = (float*)(cbT + (size_t)KDIM * DDIM);   // N
    float* invn_cb = invn_h + NROWS;                        // K
    int*   ws_idx  = (int*)(invn_cb + KDIM);                // N
    float* partials = (float*)(ws_idx + NROWS);             // N

    rownorms<<<NROWS / 4, 256, 0, stream>>>(h, invn_h);
    prep_cb<<<KDIM / 4, 256, 0, stream>>>(cb, cb_hi, cb_lo, invn_cb);
    transpose_cb<<<dim3(KDIM / 64, DDIM / 64), 256, 0, stream>>>(cb, invn_cb, cbT);

    gemm1_split<<<(NROWS / 128) * (KDIM / 128), 256, 0, stream>>>(
        h, cb_hi, cb_lo, invn_h, invn_cb, u, q);

    softmax_rows<<<NROWS, 256, 0, stream>>>(q, idx_f, ws_idx);

    gemm2_bf16<<<(NROWS / 128) * (DDIM / 128), 256, 0, stream>>>(q, cbT, c_tilde);

    gather_loss<<<NROWS, 256, 0, stream>>>(cb_hi, cb_lo, invn_cb, ws_idx,
                                           c_tilde, h, invn_h,
                                           c_hard, c_quant, partials);
    loss_reduce<<<1, 1024, 0, stream>>>(partials, loss);
}

// Round 2
// 1114.745 us; speedup vs baseline: 2.0706x; 1.0604x over previous
//
#include <hip/hip_runtime.h>
#include <math.h>

#define NROWS 32768   // B*T
#define DDIM  512
#define KDIM  2048

typedef unsigned short u16;
typedef unsigned int   u32;
using f32x4  = __attribute__((ext_vector_type(4))) float;
using bf16x8 = __attribute__((ext_vector_type(8))) __bf16;

// ------------------------------- helpers -----------------------------------
__device__ __forceinline__ u32 rne2(float x, float y) {
    // pack two fp32 -> two RNE bf16 in one dword (low = x)
    u32 vx = __float_as_uint(x), vy = __float_as_uint(y);
    vx = vx + 0x7fffu + ((vx >> 16) & 1u);
    vy = vy + 0x7fffu + ((vy >> 16) & 1u);
    return (vx >> 16) | (vy & 0xffff0000u);
}

// split fp32 into hi (truncated top 16 bits) + lo (RNE bf16 of residual)
__device__ __forceinline__ void split2(float x, float y, u32 &hp, u32 &lp) {
    u32 ux = __float_as_uint(x), uy = __float_as_uint(y);
    u32 hxm = ux & 0xffff0000u, hym = uy & 0xffff0000u;
    hp = (ux >> 16) | hym;
    float rx = x - __uint_as_float(hxm);
    float ry = y - __uint_as_float(hym);
    lp = rne2(rx, ry);
}

__device__ __forceinline__ float gumbel(float u) {
    return -logf(-logf(u + 1e-10f) + 1e-10f);
}

// async global->LDS, 16B per lane; LDS dest is wave-uniform base + lane*16
__device__ __forceinline__ void gload16(const void* g, void* l) {
    __builtin_amdgcn_global_load_lds(
        (const __attribute__((address_space(1))) void*)g,
        (__attribute__((address_space(3))) void*)l,
        16, 0, 0);
}

// --------------- row inverse-norms (h) + optional hi/lo split ---------------
__global__ __launch_bounds__(256) void rownorms_h(
    const float* __restrict__ X, float* __restrict__ OUT,
    u16* __restrict__ HI, u16* __restrict__ LO, int do_split)
{
    int wv = threadIdx.x >> 6, lane = threadIdx.x & 63;
    int row = blockIdx.x * 4 + wv;
    const float4* src = (const float4*)(X + (size_t)row * DDIM);
    float4 a = src[lane], b = src[lane + 64];
    float ss = a.x*a.x + a.y*a.y + a.z*a.z + a.w*a.w
             + b.x*b.x + b.y*b.y + b.z*b.z + b.w*b.w;
    #pragma unroll
    for (int off = 32; off > 0; off >>= 1) ss += __shfl_down(ss, off, 64);
    if (lane == 0) OUT[row] = 1.0f / fmaxf(sqrtf(ss), 1e-6f);
    if (do_split) {
        u32 h0, h1, l0, l1;
        split2(a.x, a.y, h0, l0); split2(a.z, a.w, h1, l1);
        *(uint2*)(HI + (size_t)row * DDIM + lane * 4) = make_uint2(h0, h1);
        *(uint2*)(LO + (size_t)row * DDIM + lane * 4) = make_uint2(l0, l1);
        split2(b.x, b.y, h0, l0); split2(b.z, b.w, h1, l1);
        *(uint2*)(HI + (size_t)row * DDIM + 256 + lane * 4) = make_uint2(h0, h1);
        *(uint2*)(LO + (size_t)row * DDIM + 256 + lane * 4) = make_uint2(l0, l1);
    }
}

// ------------- codebook prep: inv-norms + raw hi/lo bf16 split --------------
__global__ __launch_bounds__(256) void prep_cb(
    const float* __restrict__ CB, u16* __restrict__ HI, u16* __restrict__ LO,
    float* __restrict__ INVC)
{
    int wv = threadIdx.x >> 6, lane = threadIdx.x & 63;
    int row = blockIdx.x * 4 + wv;
    const float4* src = (const float4*)(CB + (size_t)row * DDIM);
    float4 a = src[lane], b = src[lane + 64];
    float ss = a.x*a.x + a.y*a.y + a.z*a.z + a.w*a.w
             + b.x*b.x + b.y*b.y + b.z*b.z + b.w*b.w;
    #pragma unroll
    for (int off = 32; off > 0; off >>= 1) ss += __shfl_down(ss, off, 64);
    if (lane == 0) INVC[row] = 1.0f / fmaxf(sqrtf(ss), 1e-6f);

    u32 h0, h1, l0, l1;
    split2(a.x, a.y, h0, l0); split2(a.z, a.w, h1, l1);
    *(uint2*)(HI + (size_t)row * DDIM + lane * 4) = make_uint2(h0, h1);
    *(uint2*)(LO + (size_t)row * DDIM + lane * 4) = make_uint2(l0, l1);
    split2(b.x, b.y, h0, l0); split2(b.z, b.w, h1, l1);
    *(uint2*)(HI + (size_t)row * DDIM + 256 + lane * 4) = make_uint2(h0, h1);
    *(uint2*)(LO + (size_t)row * DDIM + 256 + lane * 4) = make_uint2(l0, l1);
}

// ---- codebook transpose: CBT[d][k] = bf16(cb[k][d] * invc[k])  [512 x 2048]
__global__ __launch_bounds__(256) void transpose_cb(
    const float* __restrict__ CB, const float* __restrict__ INVC,
    u16* __restrict__ CBT)
{
    __shared__ __align__(16) u16 T[64][72];
    int t = threadIdx.x;
    int k0 = blockIdx.x * 64, d0 = blockIdx.y * 64;
    int r = t >> 2, q = (t & 3) * 16;
    float ic = INVC[k0 + r];
    const float* src = CB + (size_t)(k0 + r) * DDIM + d0 + q;
    float4 f0 = *(const float4*)(src);
    float4 f1 = *(const float4*)(src + 4);
    float4 f2 = *(const float4*)(src + 8);
    float4 f3 = *(const float4*)(src + 12);
    f0.x *= ic; f0.y *= ic; f0.z *= ic; f0.w *= ic;
    f1.x *= ic; f1.y *= ic; f1.z *= ic; f1.w *= ic;
    f2.x *= ic; f2.y *= ic; f2.z *= ic; f2.w *= ic;
    f3.x *= ic; f3.y *= ic; f3.z *= ic; f3.w *= ic;
    uint4 p0 = make_uint4(rne2(f0.x,f0.y), rne2(f0.z,f0.w), rne2(f1.x,f1.y), rne2(f1.z,f1.w));
    uint4 p1 = make_uint4(rne2(f2.x,f2.y), rne2(f2.z,f2.w), rne2(f3.x,f3.y), rne2(f3.z,f3.w));
    *(uint4*)&T[r][q]     = p0;
    *(uint4*)&T[r][q + 8] = p1;
    __syncthreads();
    int d = t >> 2, kq = (t & 3) * 16;
    u16 v[16];
    #pragma unroll
    for (int i = 0; i < 16; ++i) v[i] = T[kq + i][d];
    uint4 o0 = make_uint4((u32)v[0]  | ((u32)v[1]  << 16), (u32)v[2]  | ((u32)v[3]  << 16),
                          (u32)v[4]  | ((u32)v[5]  << 16), (u32)v[6]  | ((u32)v[7]  << 16));
    uint4 o1 = make_uint4((u32)v[8]  | ((u32)v[9]  << 16), (u32)v[10] | ((u32)v[11] << 16),
                          (u32)v[12] | ((u32)v[13] << 16), (u32)v[14] | ((u32)v[15] << 16));
    u16* dst = CBT + (size_t)(d0 + d) * KDIM + k0 + kq;
    *(uint4*)dst       = o0;
    *(uint4*)(dst + 8) = o1;
}

// ===================== GEMM1 (tier A/B): gload_lds + swizzle ================
// logits = 2*(h.cb^T)*invh*invc - 2 + g(u); 3-term split bf16.
// Tile 128x128, BK=32, dbuf. LDS tile rows = 64B; swizzle unit = 2-row span
// (8 x 16B slots): phys = logical ^ (span&7). Staged linearly by gload_lds
// from inverse-swizzled global source; reads apply the same XOR. (rule #21)
__global__ __launch_bounds__(256) void gemm1_mfma(
    const u16* __restrict__ AH, const u16* __restrict__ AL,
    const u16* __restrict__ BHc, const u16* __restrict__ BLc,
    const float* __restrict__ INVH, const float* __restrict__ INVC,
    const float* __restrict__ U, float* __restrict__ L)
{
    __shared__ __align__(16) u16 S1[2][4][4096];   // 64 KiB
    int t = threadIdx.x;
    int lane = t & 63, w = t >> 6;
    int bid = blockIdx.x;
    int wg = ((bid & 7) << 9) | (bid >> 3);        // 4096 = 8*512, bijective
    int m0 = (wg >> 4) << 7;
    int n0 = (wg & 15) << 7;

    // staging slot decode: slot s -> span=s>>3, sl=(s&7)^(span&7), r=2span+(sl>>2), c=sl&3
    int sl0 = (t & 7) ^ ((t >> 3) & 7);
    int r0 = ((t >> 3) << 1) + (sl0 >> 2), c0 = sl0 & 3;
    int s1i = t + 256;
    int sl1 = (s1i & 7) ^ ((s1i >> 3) & 7);
    int r1 = ((s1i >> 3) << 1) + (sl1 >> 2), c1 = sl1 & 3;

    const u16* gA0h = AH  + (size_t)(m0 + r0) * DDIM + c0 * 8;
    const u16* gA1h = AH  + (size_t)(m0 + r1) * DDIM + c1 * 8;
    const u16* gA0l = AL  + (size_t)(m0 + r0) * DDIM + c0 * 8;
    const u16* gA1l = AL  + (size_t)(m0 + r1) * DDIM + c1 * 8;
    const u16* gB0h = BHc + (size_t)(n0 + r0) * DDIM + c0 * 8;
    const u16* gB1h = BHc + (size_t)(n0 + r1) * DDIM + c1 * 8;
    const u16* gB0l = BLc + (size_t)(n0 + r0) * DDIM + c0 * 8;
    const u16* gB1l = BLc + (size_t)(n0 + r1) * DDIM + c1 * 8;

    int d0 = w * 512, d1 = w * 512 + 2048;         // u16 offsets, issues 0/1

    int wr = (w >> 1) << 6, wc = (w & 1) << 6;
    int frow = lane & 15, ck = lane >> 4;
    int offA[4], offB[4];
    #pragma unroll
    for (int i = 0; i < 4; ++i) {
        int R  = wr + i * 16 + frow;
        offA[i] = (R >> 1) * 64 + (((((R & 1) << 2) | ck) ^ ((R >> 1) & 7)) << 3);
        int Rb = wc + i * 16 + frow;
        offB[i] = (Rb >> 1) * 64 + (((((Rb & 1) << 2) | ck) ^ ((Rb >> 1) & 7)) << 3);
    }

    f32x4 acc[4][4];
    #pragma unroll
    for (int i = 0; i < 4; ++i)
        #pragma unroll
        for (int j = 0; j < 4; ++j)
            acc[i][j] = (f32x4){0.0f, 0.0f, 0.0f, 0.0f};

#define STAGE1(bs, ko) do { \
    gload16(gA0h + (ko), &S1[bs][0][d0]); gload16(gA1h + (ko), &S1[bs][0][d1]); \
    gload16(gA0l + (ko), &S1[bs][1][d0]); gload16(gA1l + (ko), &S1[bs][1][d1]); \
    gload16(gB0h + (ko), &S1[bs][2][d0]); gload16(gB1h + (ko), &S1[bs][2][d1]); \
    gload16(gB0l + (ko), &S1[bs][3][d0]); gload16(gB1l + (ko), &S1[bs][3][d1]); \
} while (0)

    STAGE1(0, 0);
    __syncthreads();
    int cur = 0;
    #pragma unroll 1
    for (int kt = 0; kt < 16; ++kt) {
        if (kt < 15) STAGE1(cur ^ 1, (kt + 1) * 32);   // overlap with MFMAs
        bf16x8 vbh[4], vbl[4];
        #pragma unroll
        for (int j = 0; j < 4; ++j) {
            vbh[j] = *(const bf16x8*)&S1[cur][2][offB[j]];
            vbl[j] = *(const bf16x8*)&S1[cur][3][offB[j]];
        }
        #pragma unroll
        for (int i = 0; i < 4; ++i) {
            bf16x8 vah = *(const bf16x8*)&S1[cur][0][offA[i]];
            bf16x8 val = *(const bf16x8*)&S1[cur][1][offA[i]];
            #pragma unroll
            for (int j = 0; j < 4; ++j) {
                acc[i][j] = __builtin_amdgcn_mfma_f32_16x16x32_bf16(vah, vbh[j], acc[i][j], 0, 0, 0);
                acc[i][j] = __builtin_amdgcn_mfma_f32_16x16x32_bf16(vah, vbl[j], acc[i][j], 0, 0, 0);
                acc[i][j] = __builtin_amdgcn_mfma_f32_16x16x32_bf16(val, vbh[j], acc[i][j], 0, 0, 0);
            }
        }
        __syncthreads();   // vmcnt(0)+lgkmcnt(0)+barrier: stage done, reads done
        cur ^= 1;
    }
#undef STAGE1

    float invc[4];
    #pragma unroll
    for (int j = 0; j < 4; ++j) invc[j] = INVC[n0 + wc + j * 16 + frow];
    int rr0 = ck << 2;
    #pragma unroll
    for (int i = 0; i < 4; ++i) {
        #pragma unroll
        for (int r = 0; r < 4; ++r) {
            int grow = m0 + wr + i * 16 + rr0 + r;
            float ih = INVH[grow];
            const float* urow = U + (size_t)grow * KDIM + n0 + wc + frow;
            float*       lrow = L + (size_t)grow * KDIM + n0 + wc + frow;
            #pragma unroll
            for (int j = 0; j < 4; ++j) {
                float s = acc[i][j][r] * ih * invc[j];
                lrow[j * 16] = 2.0f * s - 2.0f + gumbel(urow[j * 16]);
            }
        }
    }
}

// ============ GEMM1 (tier C fallback): round-1 reg-staged version ===========
#define LDS1 40
__global__ __launch_bounds__(256) void gemm1_split(
    const float* __restrict__ H, const u16* __restrict__ BH,
    const u16* __restrict__ BL, const float* __restrict__ INVH,
    const float* __restrict__ INVC, const float* __restrict__ U,
    float* __restrict__ L)
{
    __shared__ __align__(16) u16 Ah[128 * LDS1];
    __shared__ __align__(16) u16 Al[128 * LDS1];
    __shared__ __align__(16) u16 Bh[128 * LDS1];
    __shared__ __align__(16) u16 Bl[128 * LDS1];

    int t = threadIdx.x;
    int bid = blockIdx.x;
    int w = ((bid & 7) << 9) | (bid >> 3);
    int m0 = (w >> 4) * 128;
    int n0 = (w & 15) * 128;

    int srow = t >> 1;
    int scol = (t & 1) << 4;

    const float* ga  = H  + (size_t)(m0 + srow) * DDIM + scol;
    const u16*   gbh = BH + (size_t)(n0 + srow) * DDIM + scol;
    const u16*   gbl = BL + (size_t)(n0 + srow) * DDIM + scol;

    float4 a0 = *(const float4*)(ga);
    float4 a1 = *(const float4*)(ga + 4);
    float4 a2 = *(const float4*)(ga + 8);
    float4 a3 = *(const float4*)(ga + 12);
    uint4  b0 = *(const uint4*)(gbh);
    uint4  b1 = *(const uint4*)(gbh + 8);
    uint4  c0 = *(const uint4*)(gbl);
    uint4  c1 = *(const uint4*)(gbl + 8);

    f32x4 acc[4][4];
    #pragma unroll
    for (int i = 0; i < 4; ++i)
        #pragma unroll
        for (int j = 0; j < 4; ++j)
            acc[i][j] = (f32x4){0.0f, 0.0f, 0.0f, 0.0f};

    int lane = t & 63;
    int wid  = t >> 6;
    int wr = (wid >> 1) << 6;
    int wc = (wid & 1) << 6;
    int frow = lane & 15;
    int fk   = (lane >> 4) << 3;
    int asb  = srow * LDS1 + scol;

    #pragma unroll 1
    for (int kt = 0; kt < 16; ++kt) {
        uint4 hA, lA;
        split2(a0.x, a0.y, hA.x, lA.x);
        split2(a0.z, a0.w, hA.y, lA.y);
        split2(a1.x, a1.y, hA.z, lA.z);
        split2(a1.z, a1.w, hA.w, lA.w);
        *(uint4*)&Ah[asb] = hA;
        *(uint4*)&Al[asb] = lA;
        split2(a2.x, a2.y, hA.x, lA.x);
        split2(a2.z, a2.w, hA.y, lA.y);
        split2(a3.x, a3.y, hA.z, lA.z);
        split2(a3.z, a3.w, hA.w, lA.w);
        *(uint4*)&Ah[asb + 8] = hA;
        *(uint4*)&Al[asb + 8] = lA;
        *(uint4*)&Bh[asb]     = b0;
        *(uint4*)&Bh[asb + 8] = b1;
        *(uint4*)&Bl[asb]     = c0;
        *(uint4*)&Bl[asb + 8] = c1;
        __syncthreads();
        if (kt < 15) {
            ga += 32; gbh += 32; gbl += 32;
            a0 = *(const float4*)(ga);
            a1 = *(const float4*)(ga + 4);
            a2 = *(const float4*)(ga + 8);
            a3 = *(const float4*)(ga + 12);
            b0 = *(const uint4*)(gbh);
            b1 = *(const uint4*)(gbh + 8);
            c0 = *(const uint4*)(gbl);
            c1 = *(const uint4*)(gbl + 8);
        }
        bf16x8 vbh[4], vbl[4];
        #pragma unroll
        for (int j = 0; j < 4; ++j) {
            int off = (wc + j * 16 + frow) * LDS1 + fk;
            vbh[j] = *(const bf16x8*)&Bh[off];
            vbl[j] = *(const bf16x8*)&Bl[off];
        }
        #pragma unroll
        for (int i = 0; i < 4; ++i) {
            int off = (wr + i * 16 + frow) * LDS1 + fk;
            bf16x8 vah = *(const bf16x8*)&Ah[off];
            bf16x8 val = *(const bf16x8*)&Al[off];
            #pragma unroll
            for (int j = 0; j < 4; ++j) {
                acc[i][j] = __builtin_amdgcn_mfma_f32_16x16x32_bf16(vah, vbh[j], acc[i][j], 0, 0, 0);
                acc[i][j] = __builtin_amdgcn_mfma_f32_16x16x32_bf16(vah, vbl[j], acc[i][j], 0, 0, 0);
                acc[i][j] = __builtin_amdgcn_mfma_f32_16x16x32_bf16(val, vbh[j], acc[i][j], 0, 0, 0);
            }
        }
        __syncthreads();
    }

    float invc[4];
    #pragma unroll
    for (int j = 0; j < 4; ++j) invc[j] = INVC[n0 + wc + j * 16 + frow];
    int r0 = (lane >> 4) << 2;
    #pragma unroll
    for (int i = 0; i < 4; ++i) {
        #pragma unroll
        for (int r = 0; r < 4; ++r) {
            int grow = m0 + wr + i * 16 + r0 + r;
            float ih = INVH[grow];
            const float* urow = U + (size_t)grow * KDIM + n0 + wc + frow;
            float*       lrow = L + (size_t)grow * KDIM + n0 + wc + frow;
            #pragma unroll
            for (int j = 0; j < 4; ++j) {
                float s = acc[i][j][r] * ih * invc[j];
                lrow[j * 16] = 2.0f * s - 2.0f + gumbel(urow[j * 16]);
            }
        }
    }
}

// ------- softmax + argmax per row; optionally emit E=exp(l-m) bf16 + 1/sum --
__global__ __launch_bounds__(256) void softmax_rows(
    float* __restrict__ L, float* __restrict__ out_idx_f, int* __restrict__ ws_idx,
    u16* __restrict__ E, float* __restrict__ SINV, int we)
{
    int row = blockIdx.x, t = threadIdx.x;
    int lane = t & 63, wv = t >> 6;
    float* lr = L + (size_t)row * KDIM;
    float4 v0 = ((float4*)lr)[t];
    float4 v1 = ((float4*)lr)[t + 256];
    int c0 = t * 4, c1 = 1024 + t * 4;
    float m = v0.x; int mi = c0;
    if (v0.y > m) { m = v0.y; mi = c0 + 1; }
    if (v0.z > m) { m = v0.z; mi = c0 + 2; }
    if (v0.w > m) { m = v0.w; mi = c0 + 3; }
    if (v1.x > m) { m = v1.x; mi = c1; }
    if (v1.y > m) { m = v1.y; mi = c1 + 1; }
    if (v1.z > m) { m = v1.z; mi = c1 + 2; }
    if (v1.w > m) { m = v1.w; mi = c1 + 3; }
    #pragma unroll
    for (int off = 32; off > 0; off >>= 1) {
        float om = __shfl_down(m, off, 64);
        int   oi = __shfl_down(mi, off, 64);
        if (om > m || (om == m && oi < mi)) { m = om; mi = oi; }
    }
    __shared__ float wm[4]; __shared__ int wi[4]; __shared__ float wsum[4];
    if (lane == 0) { wm[wv] = m; wi[wv] = mi; }
    __syncthreads();
    float M = wm[0]; int MI = wi[0];
    #pragma unroll
    for (int k = 1; k < 4; ++k)
        if (wm[k] > M || (wm[k] == M && wi[k] < MI)) { M = wm[k]; MI = wi[k]; }
    v0.x = expf(v0.x - M); v0.y = expf(v0.y - M);
    v0.z = expf(v0.z - M); v0.w = expf(v0.w - M);
    v1.x = expf(v1.x - M); v1.y = expf(v1.y - M);
    v1.z = expf(v1.z - M); v1.w = expf(v1.w - M);
    float s = v0.x + v0.y + v0.z + v0.w + v1.x + v1.y + v1.z + v1.w;
    #pragma unroll
    for (int off = 32; off > 0; off >>= 1) s += __shfl_down(s, off, 64);
    if (lane == 0) wsum[wv] = s;
    __syncthreads();
    float inv = 1.0f / (wsum[0] + wsum[1] + wsum[2] + wsum[3]);
    if (we) {
        *(uint2*)(E + (size_t)row * KDIM + 4 * t) =
            make_uint2(rne2(v0.x, v0.y), rne2(v0.z, v0.w));
        *(uint2*)(E + (size_t)row * KDIM + 1024 + 4 * t) =
            make_uint2(rne2(v1.x, v1.y), rne2(v1.z, v1.w));
        if (t == 0) SINV[row] = inv;
    }
    v0.x *= inv; v0.y *= inv; v0.z *= inv; v0.w *= inv;
    v1.x *= inv; v1.y *= inv; v1.z *= inv; v1.w *= inv;
    ((float4*)lr)[t] = v0;
    ((float4*)lr)[t + 256] = v1;
    if (t == 0) { out_idx_f[row] = (float)MI; ws_idx[row] = MI; }
}

// ========== GEMM2 (tier A): c_tilde = (E . cbT^T) * sinv, gload_lds =========
// Tile 128x128, BK=64, dbuf. Rows = 128B = 8 x 16B slots; phys = c ^ (r&7).
__global__ __launch_bounds__(256) void gemm2_e(
    const u16* __restrict__ E, const u16* __restrict__ CBT,
    const float* __restrict__ SINV, float* __restrict__ CT)
{
    __shared__ __align__(16) u16 S2[2][2][8192];   // 64 KiB
    int t = threadIdx.x;
    int lane = t & 63, w = t >> 6;
    int bid = blockIdx.x;
    int wg = ((bid & 7) << 7) | (bid >> 3);        // 1024 = 8*128, bijective
    int m0 = (wg >> 2) << 7;
    int n0 = (wg & 3) << 7;

    int rr[4], cc[4];
    #pragma unroll
    for (int I = 0; I < 4; ++I) {
        int s = t + I * 256;
        rr[I] = s >> 3;
        cc[I] = (s & 7) ^ (rr[I] & 7);
    }
    const u16* ge0 = E   + (size_t)(m0 + rr[0]) * KDIM + cc[0] * 8;
    const u16* ge1 = E   + (size_t)(m0 + rr[1]) * KDIM + cc[1] * 8;
    const u16* ge2 = E   + (size_t)(m0 + rr[2]) * KDIM + cc[2] * 8;
    const u16* ge3 = E   + (size_t)(m0 + rr[3]) * KDIM + cc[3] * 8;
    const u16* gb0 = CBT + (size_t)(n0 + rr[0]) * KDIM + cc[0] * 8;
    const u16* gb1 = CBT + (size_t)(n0 + rr[1]) * KDIM + cc[1] * 8;
    const u16* gb2 = CBT + (size_t)(n0 + rr[2]) * KDIM + cc[2] * 8;
    const u16* gb3 = CBT + (size_t)(n0 + rr[3]) * KDIM + cc[3] * 8;

    int dA0 = w * 512, dA1 = w * 512 + 2048, dA2 = w * 512 + 4096, dA3 = w * 512 + 6144;

    int wr = (w >> 1) << 6, wc = (w & 1) << 6;
    int frow = lane & 15, ck = lane >> 4;
    int offA[4][2], offB[4][2];
    #pragma unroll
    for (int i = 0; i < 4; ++i) {
        int R  = wr + i * 16 + frow;
        int Rb = wc + i * 16 + frow;
        #pragma unroll
        for (int kk = 0; kk < 2; ++kk) {
            int ch = kk * 4 + ck;
            offA[i][kk] = R  * 64 + ((ch ^ (R  & 7)) << 3);
            offB[i][kk] = Rb * 64 + ((ch ^ (Rb & 7)) << 3);
        }
    }

    f32x4 acc[4][4];
    #pragma unroll
    for (int i = 0; i < 4; ++i)
        #pragma unroll
        for (int j = 0; j < 4; ++j)
            acc[i][j] = (f32x4){0.0f, 0.0f, 0.0f, 0.0f};

#define STAGE2(bs, ko) do { \
    gload16(ge0 + (ko), &S2[bs][0][dA0]); gload16(ge1 + (ko), &S2[bs][0][dA1]); \
    gload16(ge2 + (ko), &S2[bs][0][dA2]); gload16(ge3 + (ko), &S2[bs][0][dA3]); \
    gload16(gb0 + (ko), &S2[bs][1][dA0]); gload16(gb1 + (ko), &S2[bs][1][dA1]); \
    gload16(gb2 + (ko), &S2[bs][1][dA2]); gload16(gb3 + (ko), &S2[bs][1][dA3]); \
} while (0)

    STAGE2(0, 0);
    __syncthreads();
    int cur = 0;
    #pragma unroll 1
    for (int kt = 0; kt < 32; ++kt) {
        if (kt < 31) STAGE2(cur ^ 1, (kt + 1) * 64);
        #pragma unroll
        for (int kk = 0; kk < 2; ++kk) {
            bf16x8 vb[4];
            #pragma unroll
            for (int j = 0; j < 4; ++j)
                vb[j] = *(const bf16x8*)&S2[cur][1][offB[j][kk]];
            #pragma unroll
            for (int i = 0; i < 4; ++i) {
                bf16x8 va = *(const bf16x8*)&S2[cur][0][offA[i][kk]];
                #pragma unroll
                for (int j = 0; j < 4; ++j)
                    acc[i][j] = __builtin_amdgcn_mfma_f32_16x16x32_bf16(va, vb[j], acc[i][j], 0, 0, 0);
            }
        }
        __syncthreads();
        cur ^= 1;
    }
#undef STAGE2

    int rr0 = ck << 2;
    #pragma unroll
    for (int i = 0; i < 4; ++i) {
        #pragma unroll
        for (int r = 0; r < 4; ++r) {
            int grow = m0 + wr + i * 16 + rr0 + r;
            float sv = SINV[grow];
            float* crow = CT + (size_t)grow * DDIM + n0 + wc + frow;
            #pragma unroll
            for (int j = 0; j < 4; ++j) crow[j * 16] = acc[i][j][r] * sv;
        }
    }
}

// ====== GEMM2 (tier B/C fallback): round-1 reg-staged q fp32 -> bf16 ========
#define LDS2 72
__global__ __launch_bounds__(256) void gemm2_bf16(
    const float* __restrict__ Q, const u16* __restrict__ CBT, float* __restrict__ CT)
{
    __shared__ __align__(16) u16 As[128 * LDS2];
    __shared__ __align__(16) u16 Bs[128 * LDS2];
    int t = threadIdx.x;
    int bid = blockIdx.x;
    int w = ((bid & 7) << 7) | (bid >> 3);
    int m0 = (w >> 2) * 128;
    int n0 = (w & 3) * 128;
    int srow = t >> 1;
    int scol = (t & 1) << 5;
    const float* gq = Q   + (size_t)(m0 + srow) * KDIM + scol;
    const u16*   gb = CBT + (size_t)(n0 + srow) * KDIM + scol;

    float4 q0 = *(const float4*)(gq);
    float4 q1 = *(const float4*)(gq + 4);
    float4 q2 = *(const float4*)(gq + 8);
    float4 q3 = *(const float4*)(gq + 12);
    float4 q4 = *(const float4*)(gq + 16);
    float4 q5 = *(const float4*)(gq + 20);
    float4 q6 = *(const float4*)(gq + 24);
    float4 q7 = *(const float4*)(gq + 28);
    uint4 b0 = *(const uint4*)(gb);
    uint4 b1 = *(const uint4*)(gb + 8);
    uint4 b2 = *(const uint4*)(gb + 16);
    uint4 b3 = *(const uint4*)(gb + 24);

    f32x4 acc[4][4];
    #pragma unroll
    for (int i = 0; i < 4; ++i)
        #pragma unroll
        for (int j = 0; j < 4; ++j)
            acc[i][j] = (f32x4){0.0f, 0.0f, 0.0f, 0.0f};

    int lane = t & 63, wid = t >> 6;
    int wr = (wid >> 1) << 6;
    int wc = (wid & 1) << 6;
    int frow = lane & 15;
    int fk   = (lane >> 4) << 3;
    int asb  = srow * LDS2 + scol;

    #pragma unroll 1
    for (int kt = 0; kt < 32; ++kt) {
        uint4 pa;
        pa = make_uint4(rne2(q0.x,q0.y), rne2(q0.z,q0.w), rne2(q1.x,q1.y), rne2(q1.z,q1.w));
        *(uint4*)&As[asb] = pa;
        pa = make_uint4(rne2(q2.x,q2.y), rne2(q2.z,q2.w), rne2(q3.x,q3.y), rne2(q3.z,q3.w));
        *(uint4*)&As[asb + 8] = pa;
        pa = make_uint4(rne2(q4.x,q4.y), rne2(q4.z,q4.w), rne2(q5.x,q5.y), rne2(q5.z,q5.w));
        *(uint4*)&As[asb + 16] = pa;
        pa = make_uint4(rne2(q6.x,q6.y), rne2(q6.z,q6.w), rne2(q7.x,q7.y), rne2(q7.z,q7.w));
        *(uint4*)&As[asb + 24] = pa;
        *(uint4*)&Bs[asb]      = b0;
        *(uint4*)&Bs[asb + 8]  = b1;
        *(uint4*)&Bs[asb + 16] = b2;
        *(uint4*)&Bs[asb + 24] = b3;
        __syncthreads();
        if (kt < 31) {
            gq += 64; gb += 64;
            q0 = *(const float4*)(gq);
            q1 = *(const float4*)(gq + 4);
            q2 = *(const float4*)(gq + 8);
            q3 = *(const float4*)(gq + 12);
            q4 = *(const float4*)(gq + 16);
            q5 = *(const float4*)(gq + 20);
            q6 = *(const float4*)(gq + 24);
            q7 = *(const float4*)(gq + 28);
            b0 = *(const uint4*)(gb);
            b1 = *(const uint4*)(gb + 8);
            b2 = *(const uint4*)(gb + 16);
            b3 = *(const uint4*)(gb + 24);
        }
        #pragma unroll
        for (int kk = 0; kk < 2; ++kk) {
            bf16x8 vb[4];
            #pragma unroll
            for (int j = 0; j < 4; ++j)
                vb[j] = *(const bf16x8*)&Bs[(wc + j * 16 + frow) * LDS2 + kk * 32 + fk];
            #pragma unroll
            for (int i = 0; i < 4; ++i) {
                bf16x8 va = *(const bf16x8*)&As[(wr + i * 16 + frow) * LDS2 + kk * 32 + fk];
                #pragma unroll
                for (int j = 0; j < 4; ++j)
                    acc[i][j] = __builtin_amdgcn_mfma_f32_16x16x32_bf16(va, vb[j], acc[i][j], 0, 0, 0);
            }
        }
        __syncthreads();
    }

    int r0 = (lane >> 4) << 2;
    #pragma unroll
    for (int i = 0; i < 4; ++i) {
        #pragma unroll
        for (int r = 0; r < 4; ++r) {
            int grow = m0 + wr + i * 16 + r0 + r;
            float* crow = CT + (size_t)grow * DDIM + n0 + wc + frow;
            #pragma unroll
            for (int j = 0; j < 4; ++j) crow[j * 16] = acc[i][j][r];
        }
    }
}

// ---------------- gather c_hard/c_quant + per-row squared-diff partials -----
__global__ __launch_bounds__(256) void gather_loss(
    const u16* __restrict__ CBH, const u16* __restrict__ CBL,
    const float* __restrict__ INVC, const int* __restrict__ ws_idx,
    const float* __restrict__ Ct, const float* __restrict__ H,
    const float* __restrict__ INVH,
    float* __restrict__ c_hard, float* __restrict__ c_quant,
    float* __restrict__ partials)
{
    int row = blockIdx.x, t = threadIdx.x;
    int idx = ws_idx[row];
    float ic = INVC[idx], ih = INVH[row];
    u32 hp = ((const u32*)(CBH + (size_t)idx * DDIM))[t];
    u32 lp = ((const u32*)(CBL + (size_t)idx * DDIM))[t];
    float cx = (__uint_as_float(hp << 16) + __uint_as_float(lp << 16)) * ic;
    float cy = (__uint_as_float(hp & 0xffff0000u) + __uint_as_float(lp & 0xffff0000u)) * ic;
    float2 cv; cv.x = cx; cv.y = cy;
    ((float2*)(c_hard  + (size_t)row * DDIM))[t] = cv;
    ((float2*)(c_quant + (size_t)row * DDIM))[t] = cv;
    float2 hv = ((const float2*)(H  + (size_t)row * DDIM))[t];
    float2 ct = ((const float2*)(Ct + (size_t)row * DDIM))[t];
    float dx = ct.x - hv.x * ih, dy = ct.y - hv.y * ih;
    __shared__ float red[256];
    red[t] = dx * dx + dy * dy;
    __syncthreads();
    for (int s = 128; s > 0; s >>= 1) {
        if (t < s) red[t] += red[t + s];
        __syncthreads();
    }
    if (t == 0) partials[row] = red[0];
}

__global__ __launch_bounds__(1024) void loss_reduce(
    const float* __restrict__ partials, float* __restrict__ loss_out)
{
    int t = threadIdx.x;
    float s = 0.0f;
    for (int i = t; i < NROWS; i += 1024) s += partials[i];
    __shared__ float red[1024];
    red[t] = s;
    __syncthreads();
    for (int st = 512; st > 0; st >>= 1) {
        if (t < st) red[t] += red[t + st];
        __syncthreads();
    }
    if (t == 0) loss_out[0] = red[0] * (1.25f / ((float)NROWS * (float)DDIM));
}

extern "C" void kernel_launch(void* const* d_in, const int* in_sizes, int n_in,
                              void* d_out, int out_size, void* d_ws, size_t ws_size,
                              hipStream_t stream) {
    const float* h  = (const float*)d_in[0];
    const float* cb = (const float*)d_in[1];
    const float* u  = (const float*)d_in[2];

    float* out     = (float*)d_out;
    float* q       = out;                                   // N*K
    float* c_tilde = out + (size_t)NROWS * KDIM;            // N*D
    float* c_hard  = c_tilde + (size_t)NROWS * DDIM;
    float* c_quant = c_hard  + (size_t)NROWS * DDIM;
    float* loss    = c_quant + (size_t)NROWS * DDIM;        // 1
    float* idx_f   = loss + 1;                              // N

    // workspace layout (tiered on ws_size)
    char* wsp = (char*)d_ws;
    u16* cb_hi = (u16*)wsp;            wsp += (size_t)KDIM * DDIM * 2;   // 2 MB
    u16* cb_lo = (u16*)wsp;            wsp += (size_t)KDIM * DDIM * 2;   // 2 MB
    u16* cbT   = (u16*)wsp;            wsp += (size_t)DDIM * KDIM * 2;   // 2 MB
    float* invn_h  = (float*)wsp;      wsp += (size_t)NROWS * 4;         // 128 KB
    float* invn_cb = (float*)wsp;      wsp += (size_t)KDIM * 4;          // 8 KB
    float* sinv    = (float*)wsp;      wsp += (size_t)NROWS * 4;         // 128 KB
    int*   ws_idx  = (int*)wsp;        wsp += (size_t)NROWS * 4;         // 128 KB
    float* partials= (float*)wsp;      wsp += (size_t)NROWS * 4;         // 128 KB
    u16* h_hi = (u16*)wsp;             wsp += (size_t)NROWS * DDIM * 2;  // 32 MB
    u16* h_lo = (u16*)wsp;             wsp += (size_t)NROWS * DDIM * 2;  // 32 MB
    u16* Ebuf = (u16*)wsp;                                               // 128 MB

    const size_t NEED_B = 73932800ull;     // through h_lo
    const size_t NEED_A = 208150528ull;    // + Ebuf
    int tier = (ws_size >= NEED_A) ? 0 : ((ws_size >= NEED_B) ? 1 : 2);

    rownorms_h<<<NROWS / 4, 256, 0, stream>>>(h, invn_h, h_hi, h_lo, tier <= 1);
    prep_cb<<<KDIM / 4, 256, 0, stream>>>(cb, cb_hi, cb_lo, invn_cb);
    transpose_cb<<<dim3(KDIM / 64, DDIM / 64), 256, 0, stream>>>(cb, invn_cb, cbT);

    if (tier <= 1)
        gemm1_mfma<<<(NROWS / 128) * (KDIM / 128), 256, 0, stream>>>(
            h_hi, h_lo, cb_hi, cb_lo, invn_h, invn_cb, u, q);
    else
        gemm1_split<<<(NROWS / 128) * (KDIM / 128), 256, 0, stream>>>(
            h, cb_hi, cb_lo, invn_h, invn_cb, u, q);

    softmax_rows<<<NROWS, 256, 0, stream>>>(q, idx_f, ws_idx, Ebuf, sinv, tier == 0);

    if (tier == 0)
        gemm2_e<<<(NROWS / 128) * (DDIM / 128), 256, 0, stream>>>(Ebuf, cbT, sinv, c_tilde);
    else
        gemm2_bf16<<<(NROWS / 128) * (DDIM / 128), 256, 0, stream>>>(q, cbT, c_tilde);

    gather_loss<<<NROWS, 256, 0, stream>>>(cb_hi, cb_lo, invn_cb, ws_idx,
                                           c_tilde, h, invn_h,
                                           c_hard, c_quant, partials);
    loss_reduce<<<1, 1024, 0, stream>>>(partials, loss);
}